// Round 4
// baseline (1000.926 us; speedup 1.0000x reference)
//
#include <hip/hip_runtime.h>
#include <hip/hip_bf16.h>
#include <math.h>

#define ALPHA 0.2f
#define NEG_INF_V -1e30f

// Shapes fixed by the reference setup: M=50000, L=32, F=128, in_features=4096.
#define L_DIM 32
#define F_DIM 128
#define IN_FEAT (L_DIM * F_DIM)   // 4096

// Native clang vector type — required by __builtin_nontemporal_* (the HIP
// float4 class type is rejected by the builtin).
typedef float v4f __attribute__((ext_vector_type(4)));

__device__ __forceinline__ float dot4(v4f a, v4f b) {
    return fmaf(a.x, b.x, fmaf(a.y, b.y, fmaf(a.z, b.z, a.w * b.w)));
}
__device__ __forceinline__ float sum4(v4f a) { return a.x + a.y + a.z + a.w; }

// Streaming (non-temporal) 16B load/store: inputs have zero cross-block
// reuse and exceed L3 (819 MB > 256 MiB) -> bypass cache retention.
__device__ __forceinline__ v4f ldnt4(const float* p) {
    return __builtin_nontemporal_load((const v4f*)p);
}
__device__ __forceinline__ void stnt4(float* p, v4f v) {
    __builtin_nontemporal_store(v, (v4f*)p);
}
__device__ __forceinline__ v4f ld4(const float* p) {
    return *(const v4f*)p;
}

// One block (256 threads) per row m.
// Thread layout: fo = t&15 owns f in {fo*4..fo*4+3} U {64+fo*4..64+fo*4+3}
//                lg = t>>4 owns l in {lg, lg+16}
__global__ __launch_bounds__(256) void gat_row_kernel(
    const float* __restrict__ inputs,
    const float* __restrict__ a,
    float* __restrict__ out,
    int M)
{
    const int m = blockIdx.x;
    if (m >= M) return;

    const int t  = threadIdx.x;
    const int fo = t & 15;
    const int lg = t >> 4;
    const int l0 = lg;
    const int l1 = lg + 16;
    const int fA = fo * 4;
    const int fB = 64 + fo * 4;

    const float* __restrict__ row = inputs + (size_t)m * IN_FEAT;
    const float* __restrict__ a1  = a;            // [4096]
    const float* __restrict__ a2  = a + IN_FEAT;  // [128]

    // ---- coalesced streaming loads: per 16-lane group each instruction
    // covers a dense 64-float span of one l-row (256B segments)
    const v4f vA0 = ldnt4(row + l0 * F_DIM + fA);
    const v4f vB0 = ldnt4(row + l0 * F_DIM + fB);
    const v4f vA1 = ldnt4(row + l1 * F_DIM + fA);
    const v4f vB1 = ldnt4(row + l1 * F_DIM + fB);

    // `a` is tiny (16 KB) and reused by every block -> normal cached loads
    const v4f a2A  = ld4(a2 + fA);
    const v4f a2B  = ld4(a2 + fB);
    const v4f a1A0 = ld4(a1 + l0 * F_DIM + fA);
    const v4f a1B0 = ld4(a1 + l0 * F_DIM + fB);
    const v4f a1A1 = ld4(a1 + l1 * F_DIM + fA);
    const v4f a1B1 = ld4(a1 + l1 * F_DIM + fB);

    // ---- per-thread partials for its two l's
    float pn0 = dot4(vA0, a2A)  + dot4(vB0, a2B);   // s_nbr[l0] partial
    float pn1 = dot4(vA1, a2A)  + dot4(vB1, a2B);   // s_nbr[l1] partial
    float ps0 = sum4(vA0)       + sum4(vB0);        // mask-sum[l0] partial
    float ps1 = sum4(vA1)       + sum4(vB1);        // mask-sum[l1] partial
    float pq0 = dot4(vA0, a1A0) + dot4(vB0, a1B0);  // s_self partial (l0 slice)
    float pq1 = dot4(vA1, a1A1) + dot4(vB1, a1B1);  // s_self partial (l1 slice)

    // ---- reduce over the 16 fo-lanes (xor masks 1,2,4,8 stay inside group)
    #pragma unroll
    for (int off = 1; off <= 8; off <<= 1) {
        pn0 += __shfl_xor(pn0, off);
        pn1 += __shfl_xor(pn1, off);
        ps0 += __shfl_xor(ps0, off);
        ps1 += __shfl_xor(ps1, off);
        pq0 += __shfl_xor(pq0, off);
        pq1 += __shfl_xor(pq1, off);
    }

    __shared__ float s_nbr[L_DIM];
    __shared__ float msum[L_DIM];
    __shared__ float qpart[16];
    __shared__ float att[L_DIM];
    __shared__ float h_lds[4][F_DIM];

    if (fo == 0) {
        s_nbr[l0] = pn0;
        s_nbr[l1] = pn1;
        msum[l0]  = ps0;
        msum[l1]  = ps1;
        qpart[lg] = pq0 + pq1;
    }
    __syncthreads();

    // ---- softmax over the 32 l's, done by lanes 0..31 (one half-wave)
    if (t < 32) {
        float ss = 0.0f;
        #pragma unroll
        for (int i = 0; i < 16; ++i) ss += qpart[i];   // s_self (broadcast reads)
        float z = ss + s_nbr[t];
        float e = (z >= 0.0f) ? z : ALPHA * z;          // LeakyReLU(0.2)
        if (msum[t] == 0.0f) e = NEG_INF_V;             // mask
        float mx = e;
        #pragma unroll
        for (int off = 1; off <= 16; off <<= 1) mx = fmaxf(mx, __shfl_xor(mx, off));
        float p = expf(e - mx);
        float sm = p;
        #pragma unroll
        for (int off = 1; off <= 16; off <<= 1) sm += __shfl_xor(sm, off);
        att[t] = p / sm;
    }
    __syncthreads();

    // ---- weighted sum over l: h[f] = sum_l att[l] * rh[l][f]
    const float w0 = att[l0];
    const float w1 = att[l1];
    v4f hA, hB;
    hA.x = fmaf(w0, vA0.x, w1 * vA1.x);
    hA.y = fmaf(w0, vA0.y, w1 * vA1.y);
    hA.z = fmaf(w0, vA0.z, w1 * vA1.z);
    hA.w = fmaf(w0, vA0.w, w1 * vA1.w);
    hB.x = fmaf(w0, vB0.x, w1 * vB1.x);
    hB.y = fmaf(w0, vB0.y, w1 * vB1.y);
    hB.z = fmaf(w0, vB0.z, w1 * vB1.z);
    hB.w = fmaf(w0, vB0.w, w1 * vB1.w);

    // reduce over the 4 lg's resident in this wave (lanes differ in bits 4,5)
    #pragma unroll
    for (int off = 16; off <= 32; off <<= 1) {
        hA.x += __shfl_xor(hA.x, off);
        hA.y += __shfl_xor(hA.y, off);
        hA.z += __shfl_xor(hA.z, off);
        hA.w += __shfl_xor(hA.w, off);
        hB.x += __shfl_xor(hB.x, off);
        hB.y += __shfl_xor(hB.y, off);
        hB.z += __shfl_xor(hB.z, off);
        hB.w += __shfl_xor(hB.w, off);
    }

    const int w = t >> 6;        // wave id 0..3
    if ((t & 63) < 16) {         // one lane per fo per wave holds the wave total
        *(v4f*)&h_lds[w][fA] = hA;
        *(v4f*)&h_lds[w][fB] = hB;
    }
    __syncthreads();

    // ---- combine 4 wave partials, final activation, coalesced 16B store
    if (t < 32) {
        v4f h = (v4f){0.f, 0.f, 0.f, 0.f};
        #pragma unroll
        for (int wv = 0; wv < 4; ++wv) {
            v4f p4 = *(v4f*)&h_lds[wv][t * 4];
            h += p4;
        }
        h.x = (h.x > 0.0f) ? h.x : expm1f(h.x);
        h.y = (h.y > 0.0f) ? h.y : expm1f(h.y);
        h.z = (h.z > 0.0f) ? h.z : expm1f(h.z);
        h.w = (h.w > 0.0f) ? h.w : expm1f(h.w);
        stnt4(out + (size_t)m * F_DIM + t * 4, h);
    }
}

extern "C" void kernel_launch(void* const* d_in, const int* in_sizes, int n_in,
                              void* d_out, int out_size, void* d_ws, size_t ws_size,
                              hipStream_t stream) {
    const float* inputs = (const float*)d_in[0];
    const float* a      = (const float*)d_in[1];
    float* out          = (float*)d_out;
    const int M = in_sizes[0] / IN_FEAT;   // 50000

    gat_row_kernel<<<M, 256, 0, stream>>>(inputs, a, out, M);
}